// Round 3
// baseline (355.687 us; speedup 1.0000x reference)
//
#include <hip/hip_runtime.h>
#include <hip/hip_bf16.h>
#include <math.h>

// Problem constants
#define TT 1024      // tokens (B*S)
#define HD 1024      // hidden
#define NE 8         // experts
#define ID 2048      // intermediate
#define MAXSLOT 3072 // 2048 assignments + 8*127 padding, rounded up
constexpr float JEPS = 0.01f;

typedef __attribute__((ext_vector_type(8))) short bf16x8;
typedef __attribute__((ext_vector_type(4))) float f32x4;

__device__ __forceinline__ float silu_f(float v) {
    return v / (1.f + expf(-v));
}

// fp32 -> bf16 (round-to-nearest-even), raw ushort (scalar, for epilogue)
__device__ __forceinline__ unsigned short f2bf(float f) {
    unsigned int u = __float_as_uint(f);
    u += 0x7FFF + ((u >> 16) & 1);
    return (unsigned short)(u >> 16);
}

// packed fp32x4 -> bf16x4 store (v_cvt_pk_bf16_f32 path), p 8B aligned
__device__ __forceinline__ void st_bf4(unsigned short* p, float4 v) {
    __hip_bfloat162 lo = __float22bfloat162_rn(make_float2(v.x, v.y));
    __hip_bfloat162 hi = __float22bfloat162_rn(make_float2(v.z, v.w));
    union { __hip_bfloat162 h[2]; uint2 q; } pk;
    pk.h[0] = lo; pk.h[1] = hi;
    *(uint2*)p = pk.q;
}

// ---------------- Kernel 1: gating (one wave per token) ----------------
__global__ __launch_bounds__(256) void gate_kernel(
    const float* __restrict__ x, const float* __restrict__ gw,
    int* __restrict__ sel, float* __restrict__ wgt, int* __restrict__ counts)
{
    int wave = threadIdx.x >> 6;
    int lane = threadIdx.x & 63;
    int t = blockIdx.x * 4 + wave;

    const float4* x4 = (const float4*)(x + (size_t)t * HD);
    const float4* g4 = (const float4*)gw;

    float acc[8] = {0.f,0.f,0.f,0.f,0.f,0.f,0.f,0.f};
    #pragma unroll
    for (int c = 0; c < 4; ++c) {
        float4 xv = x4[lane + c * 64];
        #pragma unroll
        for (int e = 0; e < 8; ++e) {
            float4 gv = g4[e * 256 + lane + c * 64];
            acc[e] += xv.x*gv.x + xv.y*gv.y + xv.z*gv.z + xv.w*gv.w;
        }
    }
    #pragma unroll
    for (int e = 0; e < 8; ++e) {
        float v = acc[e];
        #pragma unroll
        for (int off = 32; off > 0; off >>= 1) v += __shfl_xor(v, off, 64);
        acc[e] = v;
    }

    if (lane == 0) {
        float s[8];
        #pragma unroll
        for (int e = 0; e < 8; ++e) s[e] = acc[e];

        int i0 = 0; float t1 = s[0];
        #pragma unroll
        for (int e = 1; e < 8; ++e) { if (s[e] > t1) { t1 = s[e]; i0 = e; } }
        int i1 = -1; float t2 = -INFINITY;
        #pragma unroll
        for (int e = 0; e < 8; ++e) {
            if (e == i0) continue;
            if (s[e] > t2) { t2 = s[e]; i1 = e; }
        }

        float sum1 = 0.f;
        #pragma unroll
        for (int e = 0; e < 8; ++e) {
            if (e == i0) { sum1 += 1.f; continue; }
            float f = fmaxf(fabsf(s[e]), t1);
            bool masked = (t1 - s[e]) > 2.f * JEPS * f;
            if (!masked) sum1 += expf(s[e] - t1);
        }
        float w0 = 1.f / sum1;

        float sum2 = 0.f;
        #pragma unroll
        for (int e = 0; e < 8; ++e) {
            if (e == i0) continue;
            if (e == i1) { sum2 += 1.f; continue; }
            float f = fmaxf(fabsf(s[e]), t2);
            bool masked = (t2 - s[e]) > 2.f * JEPS * f;
            if (!masked) sum2 += expf(s[e] - t2);
        }
        float w1v = 1.f / sum2;

        sel[t * 2 + 0] = i0; sel[t * 2 + 1] = i1;
        wgt[t * 2 + 0] = w0; wgt[t * 2 + 1] = w1v;
        atomicAdd(&counts[i0], 1);
        atomicAdd(&counts[i1], 1);
    }
}

// ---------------- Kernel 2: padded prefix offsets (pad to 128) ----------------
__global__ void offsets_kernel(const int* __restrict__ counts,
                               int* __restrict__ offs, int* __restrict__ cursor)
{
    int o = 0;
    for (int e = 0; e < NE; ++e) {
        offs[e] = o;
        cursor[e] = o;
        o += (counts[e] + 127) & ~127;
    }
}

// ---------------- Kernel 3: scatter tokens to expert slots ----------------
__global__ __launch_bounds__(256) void scatter_kernel(
    const int* __restrict__ sel, const float* __restrict__ wgt,
    int* __restrict__ cursor, int* __restrict__ slot_token,
    float* __restrict__ slot_weight)
{
    int t = blockIdx.x * 256 + threadIdx.x;
    #pragma unroll
    for (int j = 0; j < 2; ++j) {
        int e = sel[t * 2 + j];
        int pos = atomicAdd(&cursor[e], 1);
        slot_token[pos] = t;
        slot_weight[pos] = wgt[t * 2 + j];
    }
}

// ---------------- Kernel 4: FFN1 (MFMA bf16, double-buffered pipeline) ----------------
// Tile: 128 slots x 64 intermediate, BK=32. 4 waves as 2x2, each 64x32 (4x2 frags).
// grid (tt=8, it=32, e=8), block 256.
__global__ __launch_bounds__(256) void ffn1_kernel(
    const float* __restrict__ x, const float* __restrict__ w1,
    const float* __restrict__ w3, const int* __restrict__ counts,
    const int* __restrict__ offs, const int* __restrict__ slot_token,
    unsigned short* __restrict__ act)
{
    int e = blockIdx.z, it = blockIdx.y, tt = blockIdx.x;
    int cnt = counts[e];
    if (tt * 128 >= cnt) return;
    int base = offs[e];

    __shared__ unsigned short Xs[2][128][40];   // 20 KB   [buf][slot-row][k]
    __shared__ unsigned short W1s[2][64][40];   // 10 KB
    __shared__ unsigned short W3s[2][64][40];   // 10 KB

    int t = threadIdx.x;
    // X staging: 2 threads/row, 4 float4-segs each
    int xr = t >> 1, xs0 = (t & 1) * 4;
    int srow = tt * 128 + xr;
    int tok = (srow < cnt) ? slot_token[base + srow] : slot_token[base];
    const float* xptr = x + (size_t)tok * HD;
    // W staging: 4 threads/row, segs ws0 and ws0+4
    int wrow = t >> 2, ws0 = t & 3;
    const float* w1ptr = w1 + ((size_t)e * ID + (size_t)it * 64 + wrow) * HD;
    const float* w3ptr = w3 + ((size_t)e * ID + (size_t)it * 64 + wrow) * HD;

    int wid = t >> 6, lane = t & 63;
    int wr = wid >> 1, wc = wid & 1;
    int fr = lane & 15, fg = lane >> 4;

    f32x4 a1[4][2], a3[4][2];
    #pragma unroll
    for (int m = 0; m < 4; ++m)
        #pragma unroll
        for (int n = 0; n < 2; ++n) {
            a1[m][n] = (f32x4){0.f, 0.f, 0.f, 0.f};
            a3[m][n] = (f32x4){0.f, 0.f, 0.f, 0.f};
        }

    float4 pxv[4], pw1[2], pw3[2];
    // prologue: load + stage K-tile 0 into buf 0
    #pragma unroll
    for (int j = 0; j < 4; ++j) pxv[j] = *(const float4*)(xptr + (xs0 + j) * 4);
    pw1[0] = *(const float4*)(w1ptr + ws0 * 4);
    pw1[1] = *(const float4*)(w1ptr + (ws0 + 4) * 4);
    pw3[0] = *(const float4*)(w3ptr + ws0 * 4);
    pw3[1] = *(const float4*)(w3ptr + (ws0 + 4) * 4);
    #pragma unroll
    for (int j = 0; j < 4; ++j) st_bf4(&Xs[0][xr][(xs0 + j) * 4], pxv[j]);
    st_bf4(&W1s[0][wrow][ws0 * 4], pw1[0]);
    st_bf4(&W1s[0][wrow][(ws0 + 4) * 4], pw1[1]);
    st_bf4(&W3s[0][wrow][ws0 * 4], pw3[0]);
    st_bf4(&W3s[0][wrow][(ws0 + 4) * 4], pw3[1]);

    #pragma unroll 2
    for (int kt = 0; kt < HD; kt += 32) {
        int cur = (kt >> 5) & 1;
        __syncthreads();   // buf[cur] stores visible; buf[cur^1] reads from prev iter done
        bool more = (kt + 32) < HD;
        if (more) {
            int kn = kt + 32;
            #pragma unroll
            for (int j = 0; j < 4; ++j) pxv[j] = *(const float4*)(xptr + kn + (xs0 + j) * 4);
            pw1[0] = *(const float4*)(w1ptr + kn + ws0 * 4);
            pw1[1] = *(const float4*)(w1ptr + kn + (ws0 + 4) * 4);
            pw3[0] = *(const float4*)(w3ptr + kn + ws0 * 4);
            pw3[1] = *(const float4*)(w3ptr + kn + (ws0 + 4) * 4);
        }

        bf16x8 af[4], b1f[2], b3f[2];
        #pragma unroll
        for (int m = 0; m < 4; ++m)
            af[m] = *(const bf16x8*)&Xs[cur][wr * 64 + m * 16 + fr][fg * 8];
        #pragma unroll
        for (int n = 0; n < 2; ++n) {
            b1f[n] = *(const bf16x8*)&W1s[cur][wc * 32 + n * 16 + fr][fg * 8];
            b3f[n] = *(const bf16x8*)&W3s[cur][wc * 32 + n * 16 + fr][fg * 8];
        }
        #pragma unroll
        for (int m = 0; m < 4; ++m)
            #pragma unroll
            for (int n = 0; n < 2; ++n) {
                a1[m][n] = __builtin_amdgcn_mfma_f32_16x16x32_bf16(af[m], b1f[n], a1[m][n], 0, 0, 0);
                a3[m][n] = __builtin_amdgcn_mfma_f32_16x16x32_bf16(af[m], b3f[n], a3[m][n], 0, 0, 0);
            }

        if (more) {
            int nb = cur ^ 1;
            #pragma unroll
            for (int j = 0; j < 4; ++j) st_bf4(&Xs[nb][xr][(xs0 + j) * 4], pxv[j]);
            st_bf4(&W1s[nb][wrow][ws0 * 4], pw1[0]);
            st_bf4(&W1s[nb][wrow][(ws0 + 4) * 4], pw1[1]);
            st_bf4(&W3s[nb][wrow][ws0 * 4], pw3[0]);
            st_bf4(&W3s[nb][wrow][(ws0 + 4) * 4], pw3[1]);
        }
    }

    // epilogue: act (bf16) = silu(a1) * a3.  C/D: col=lane&15, row=(lane>>4)*4+reg
    size_t rowbase = (size_t)(base + tt * 128);
    #pragma unroll
    for (int m = 0; m < 4; ++m)
        #pragma unroll
        for (int n = 0; n < 2; ++n)
            #pragma unroll
            for (int r = 0; r < 4; ++r) {
                int lrow = wr * 64 + m * 16 + fg * 4 + r;
                int col  = it * 64 + wc * 32 + n * 16 + fr;
                float v = silu_f(a1[m][n][r]) * a3[m][n][r];
                act[(rowbase + lrow) * ID + col] = f2bf(v);
            }
}

// ---------------- Kernel 5: FFN2 (MFMA bf16, dbuf + split-K2) ----------------
// Tile: 128 slots x 64 hidden, K split in 2x1024. grid (tt=8, ht*ks=32, e=8).
__global__ __launch_bounds__(256) void ffn2_kernel(
    const unsigned short* __restrict__ act, const float* __restrict__ w2,
    const int* __restrict__ counts, const int* __restrict__ offs,
    const int* __restrict__ slot_token, const float* __restrict__ slot_weight,
    float* __restrict__ out)
{
    int e = blockIdx.z, tt = blockIdx.x;
    int ht = blockIdx.y >> 1, ks = blockIdx.y & 1;
    int cnt = counts[e];
    if (tt * 128 >= cnt) return;
    int base = offs[e];
    int k0 = ks * (ID / 2);

    __shared__ unsigned short As[2][128][40];  // 20 KB
    __shared__ unsigned short Bs[2][64][40];   // 10 KB

    int t = threadIdx.x;
    // act staging: 2 threads/row, 2 uint4-segs (16 bf16) each
    int ar = t >> 1, as0 = (t & 1) * 2;
    const unsigned short* aptr = act + (size_t)(base + tt * 128 + ar) * ID + k0;
    // w2 staging: 4 threads/row
    int wrow = t >> 2, ws0 = t & 3;
    const float* w2ptr = w2 + ((size_t)e * HD + (size_t)ht * 64 + wrow) * ID + k0;

    int wid = t >> 6, lane = t & 63;
    int wr = wid >> 1, wc = wid & 1;
    int fr = lane & 15, fg = lane >> 4;

    f32x4 acc[4][2];
    #pragma unroll
    for (int m = 0; m < 4; ++m)
        #pragma unroll
        for (int n = 0; n < 2; ++n) acc[m][n] = (f32x4){0.f, 0.f, 0.f, 0.f};

    uint4 pav[2];
    float4 pbv[2];
    pav[0] = *(const uint4*)(aptr + as0 * 8);
    pav[1] = *(const uint4*)(aptr + (as0 + 1) * 8);
    pbv[0] = *(const float4*)(w2ptr + ws0 * 4);
    pbv[1] = *(const float4*)(w2ptr + (ws0 + 4) * 4);
    *(uint4*)&As[0][ar][as0 * 8] = pav[0];
    *(uint4*)&As[0][ar][(as0 + 1) * 8] = pav[1];
    st_bf4(&Bs[0][wrow][ws0 * 4], pbv[0]);
    st_bf4(&Bs[0][wrow][(ws0 + 4) * 4], pbv[1]);

    #pragma unroll 2
    for (int kt = 0; kt < ID / 2; kt += 32) {
        int cur = (kt >> 5) & 1;
        __syncthreads();
        bool more = (kt + 32) < (ID / 2);
        if (more) {
            int kn = kt + 32;
            pav[0] = *(const uint4*)(aptr + kn + as0 * 8);
            pav[1] = *(const uint4*)(aptr + kn + (as0 + 1) * 8);
            pbv[0] = *(const float4*)(w2ptr + kn + ws0 * 4);
            pbv[1] = *(const float4*)(w2ptr + kn + (ws0 + 4) * 4);
        }

        bf16x8 af[4], bf[2];
        #pragma unroll
        for (int m = 0; m < 4; ++m)
            af[m] = *(const bf16x8*)&As[cur][wr * 64 + m * 16 + fr][fg * 8];
        #pragma unroll
        for (int n = 0; n < 2; ++n)
            bf[n] = *(const bf16x8*)&Bs[cur][wc * 32 + n * 16 + fr][fg * 8];
        #pragma unroll
        for (int m = 0; m < 4; ++m)
            #pragma unroll
            for (int n = 0; n < 2; ++n)
                acc[m][n] = __builtin_amdgcn_mfma_f32_16x16x32_bf16(af[m], bf[n], acc[m][n], 0, 0, 0);

        if (more) {
            int nb = cur ^ 1;
            *(uint4*)&As[nb][ar][as0 * 8] = pav[0];
            *(uint4*)&As[nb][ar][(as0 + 1) * 8] = pav[1];
            st_bf4(&Bs[nb][wrow][ws0 * 4], pbv[0]);
            st_bf4(&Bs[nb][wrow][(ws0 + 4) * 4], pbv[1]);
        }
    }

    #pragma unroll
    for (int m = 0; m < 4; ++m)
        #pragma unroll
        for (int r = 0; r < 4; ++r) {
            int grow = tt * 128 + wr * 64 + m * 16 + fg * 4 + r;
            if (grow < cnt) {
                int tok  = slot_token[base + grow];
                float wv = slot_weight[base + grow];
                float* orow = out + (size_t)tok * HD + ht * 64 + wc * 32;
                #pragma unroll
                for (int n = 0; n < 2; ++n)
                    atomicAdd(&orow[n * 16 + fr], wv * acc[m][n][r]);
            }
        }
}

// ---------------- host launch ----------------
extern "C" void kernel_launch(void* const* d_in, const int* in_sizes, int n_in,
                              void* d_out, int out_size, void* d_ws, size_t ws_size,
                              hipStream_t stream)
{
    const float* x  = (const float*)d_in[0];  // (1,1024,1024)
    const float* gw = (const float*)d_in[1];  // (8,1024)
    const float* w1 = (const float*)d_in[2];  // (8,2048,1024)
    const float* w2 = (const float*)d_in[3];  // (8,1024,2048)
    const float* w3 = (const float*)d_in[4];  // (8,2048,1024)
    float* out = (float*)d_out;

    char* w = (char*)d_ws;
    int*   counts      = (int*)(w + 0);
    int*   offs        = (int*)(w + 64);
    int*   cursor      = (int*)(w + 128);
    int*   sel         = (int*)(w + 256);
    float* wgt         = (float*)(w + 256 + 8192);
    int*   slot_token  = (int*)(w + 16640);                 // MAXSLOT ints
    float* slot_weight = (float*)(w + 16640 + 4 * MAXSLOT);
    unsigned short* act = (unsigned short*)(w + 65536);     // MAXSLOT * ID bf16 = 12.6 MB

    hipMemsetAsync(counts, 0, 64, stream);
    hipMemsetAsync(d_out, 0, (size_t)TT * HD * sizeof(float), stream);

    gate_kernel<<<TT / 4, 256, 0, stream>>>(x, gw, sel, wgt, counts);
    offsets_kernel<<<1, 1, 0, stream>>>(counts, offs, cursor);
    scatter_kernel<<<TT / 256, 256, 0, stream>>>(sel, wgt, cursor, slot_token, slot_weight);
    ffn1_kernel<<<dim3(8, 32, 8), 256, 0, stream>>>(x, w1, w3, counts, offs, slot_token, act);
    ffn2_kernel<<<dim3(8, 32, 8), 256, 0, stream>>>(act, w2, counts, offs, slot_token, slot_weight, out);
}

// Round 4
// 179.477 us; speedup vs baseline: 1.9818x; 1.9818x over previous
//
#include <hip/hip_runtime.h>
#include <hip/hip_bf16.h>
#include <math.h>

// Problem constants
#define TT 1024      // tokens (B*S)
#define HD 1024      // hidden
#define NE 8         // experts
#define ID 2048      // intermediate
#define MAXSLOT 3072 // 2048 assignments + 8*127 padding, rounded up
constexpr float JEPS = 0.01f;

typedef __attribute__((ext_vector_type(8))) short bf16x8;
typedef __attribute__((ext_vector_type(4))) float f32x4;

__device__ __forceinline__ float silu_f(float v) {
    return v / (1.f + expf(-v));
}

// fp32 -> bf16 (round-to-nearest-even), raw ushort (scalar, for epilogue)
__device__ __forceinline__ unsigned short f2bf(float f) {
    unsigned int u = __float_as_uint(f);
    u += 0x7FFF + ((u >> 16) & 1);
    return (unsigned short)(u >> 16);
}

// packed fp32x4 -> bf16x4 store (v_cvt_pk_bf16_f32 path), p 8B aligned
__device__ __forceinline__ void st_bf4(unsigned short* p, float4 v) {
    __hip_bfloat162 lo = __float22bfloat162_rn(make_float2(v.x, v.y));
    __hip_bfloat162 hi = __float22bfloat162_rn(make_float2(v.z, v.w));
    union { __hip_bfloat162 h[2]; uint2 q; } pk;
    pk.h[0] = lo; pk.h[1] = hi;
    *(uint2*)p = pk.q;
}

// ---------------- Kernel 0: convert x to bf16 ----------------
__global__ __launch_bounds__(256) void cvtx_kernel(
    const float* __restrict__ x, unsigned short* __restrict__ xbf)
{
    int i = (blockIdx.x * 256 + threadIdx.x) * 4;
    float4 v = *(const float4*)(x + i);
    st_bf4(&xbf[i], v);
}

// ---------------- Kernel 1: gating (one wave per token) ----------------
__global__ __launch_bounds__(256) void gate_kernel(
    const float* __restrict__ x, const float* __restrict__ gw,
    int* __restrict__ sel, float* __restrict__ wgt, int* __restrict__ counts)
{
    int wave = threadIdx.x >> 6;
    int lane = threadIdx.x & 63;
    int t = blockIdx.x * 4 + wave;

    const float4* x4 = (const float4*)(x + (size_t)t * HD);
    const float4* g4 = (const float4*)gw;

    float acc[8] = {0.f,0.f,0.f,0.f,0.f,0.f,0.f,0.f};
    #pragma unroll
    for (int c = 0; c < 4; ++c) {
        float4 xv = x4[lane + c * 64];
        #pragma unroll
        for (int e = 0; e < 8; ++e) {
            float4 gv = g4[e * 256 + lane + c * 64];
            acc[e] += xv.x*gv.x + xv.y*gv.y + xv.z*gv.z + xv.w*gv.w;
        }
    }
    #pragma unroll
    for (int e = 0; e < 8; ++e) {
        float v = acc[e];
        #pragma unroll
        for (int off = 32; off > 0; off >>= 1) v += __shfl_xor(v, off, 64);
        acc[e] = v;
    }

    if (lane == 0) {
        float s[8];
        #pragma unroll
        for (int e = 0; e < 8; ++e) s[e] = acc[e];

        int i0 = 0; float t1 = s[0];
        #pragma unroll
        for (int e = 1; e < 8; ++e) { if (s[e] > t1) { t1 = s[e]; i0 = e; } }
        int i1 = -1; float t2 = -INFINITY;
        #pragma unroll
        for (int e = 0; e < 8; ++e) {
            if (e == i0) continue;
            if (s[e] > t2) { t2 = s[e]; i1 = e; }
        }

        float sum1 = 0.f;
        #pragma unroll
        for (int e = 0; e < 8; ++e) {
            if (e == i0) { sum1 += 1.f; continue; }
            float f = fmaxf(fabsf(s[e]), t1);
            bool masked = (t1 - s[e]) > 2.f * JEPS * f;
            if (!masked) sum1 += expf(s[e] - t1);
        }
        float w0 = 1.f / sum1;

        float sum2 = 0.f;
        #pragma unroll
        for (int e = 0; e < 8; ++e) {
            if (e == i0) continue;
            if (e == i1) { sum2 += 1.f; continue; }
            float f = fmaxf(fabsf(s[e]), t2);
            bool masked = (t2 - s[e]) > 2.f * JEPS * f;
            if (!masked) sum2 += expf(s[e] - t2);
        }
        float w1v = 1.f / sum2;

        sel[t * 2 + 0] = i0; sel[t * 2 + 1] = i1;
        wgt[t * 2 + 0] = w0; wgt[t * 2 + 1] = w1v;
        atomicAdd(&counts[i0], 1);
        atomicAdd(&counts[i1], 1);
    }
}

// ---------------- Kernel 2: padded prefix offsets (pad to 128) ----------------
__global__ void offsets_kernel(const int* __restrict__ counts,
                               int* __restrict__ offs, int* __restrict__ cursor)
{
    int o = 0;
    for (int e = 0; e < NE; ++e) {
        offs[e] = o;
        cursor[e] = o;
        o += (counts[e] + 127) & ~127;
    }
}

// ---------------- Kernel 3: scatter tokens to expert slots ----------------
__global__ __launch_bounds__(256) void scatter_kernel(
    const int* __restrict__ sel, const float* __restrict__ wgt,
    int* __restrict__ cursor, int* __restrict__ slot_token,
    float* __restrict__ slot_weight)
{
    int t = blockIdx.x * 256 + threadIdx.x;
    #pragma unroll
    for (int j = 0; j < 2; ++j) {
        int e = sel[t * 2 + j];
        int pos = atomicAdd(&cursor[e], 1);
        slot_token[pos] = t;
        slot_weight[pos] = wgt[t * 2 + j];
    }
}

// ---------------- Kernel 4: FFN1 (MFMA bf16, dbuf, XCD-affine) ----------------
// 1D grid 2048: e = bid&7 (XCD), r = bid>>3, it = r&31, tt = r>>5.
__global__ __launch_bounds__(256) void ffn1_kernel(
    const unsigned short* __restrict__ xbf, const float* __restrict__ w1,
    const float* __restrict__ w3, const int* __restrict__ counts,
    const int* __restrict__ offs, const int* __restrict__ slot_token,
    unsigned short* __restrict__ act)
{
    int bid = blockIdx.x;
    int e = bid & 7;
    int r = bid >> 3;
    int it = r & 31, tt = r >> 5;
    int cnt = counts[e];
    if (tt * 128 >= cnt) return;
    int base = offs[e];

    __shared__ unsigned short Xs[2][128][40];
    __shared__ unsigned short W1s[2][64][40];
    __shared__ unsigned short W3s[2][64][40];

    int t = threadIdx.x;
    int xr = t >> 1, xs = (t & 1) * 16;
    int srow = tt * 128 + xr;
    int tok = (srow < cnt) ? slot_token[base + srow] : slot_token[base];
    const unsigned short* xptr = xbf + (size_t)tok * HD;
    int wrow = t >> 2, ws0 = t & 3;
    const float* w1ptr = w1 + ((size_t)e * ID + (size_t)it * 64 + wrow) * HD;
    const float* w3ptr = w3 + ((size_t)e * ID + (size_t)it * 64 + wrow) * HD;

    int wid = t >> 6, lane = t & 63;
    int wr = wid >> 1, wc = wid & 1;
    int fr = lane & 15, fg = lane >> 4;

    f32x4 a1[4][2], a3[4][2];
    #pragma unroll
    for (int m = 0; m < 4; ++m)
        #pragma unroll
        for (int n = 0; n < 2; ++n) {
            a1[m][n] = (f32x4){0.f, 0.f, 0.f, 0.f};
            a3[m][n] = (f32x4){0.f, 0.f, 0.f, 0.f};
        }

    uint4 pxa, pxb;
    float4 pw1[2], pw3[2];
    pxa = *(const uint4*)(xptr + xs);
    pxb = *(const uint4*)(xptr + xs + 8);
    pw1[0] = *(const float4*)(w1ptr + ws0 * 4);
    pw1[1] = *(const float4*)(w1ptr + (ws0 + 4) * 4);
    pw3[0] = *(const float4*)(w3ptr + ws0 * 4);
    pw3[1] = *(const float4*)(w3ptr + (ws0 + 4) * 4);
    *(uint4*)&Xs[0][xr][xs] = pxa;
    *(uint4*)&Xs[0][xr][xs + 8] = pxb;
    st_bf4(&W1s[0][wrow][ws0 * 4], pw1[0]);
    st_bf4(&W1s[0][wrow][(ws0 + 4) * 4], pw1[1]);
    st_bf4(&W3s[0][wrow][ws0 * 4], pw3[0]);
    st_bf4(&W3s[0][wrow][(ws0 + 4) * 4], pw3[1]);

    #pragma unroll 2
    for (int kt = 0; kt < HD; kt += 32) {
        int cur = (kt >> 5) & 1;
        __syncthreads();
        bool more = (kt + 32) < HD;
        if (more) {
            int kn = kt + 32;
            pxa = *(const uint4*)(xptr + kn + xs);
            pxb = *(const uint4*)(xptr + kn + xs + 8);
            pw1[0] = *(const float4*)(w1ptr + kn + ws0 * 4);
            pw1[1] = *(const float4*)(w1ptr + kn + (ws0 + 4) * 4);
            pw3[0] = *(const float4*)(w3ptr + kn + ws0 * 4);
            pw3[1] = *(const float4*)(w3ptr + kn + (ws0 + 4) * 4);
        }

        bf16x8 af[4], b1f[2], b3f[2];
        #pragma unroll
        for (int m = 0; m < 4; ++m)
            af[m] = *(const bf16x8*)&Xs[cur][wr * 64 + m * 16 + fr][fg * 8];
        #pragma unroll
        for (int n = 0; n < 2; ++n) {
            b1f[n] = *(const bf16x8*)&W1s[cur][wc * 32 + n * 16 + fr][fg * 8];
            b3f[n] = *(const bf16x8*)&W3s[cur][wc * 32 + n * 16 + fr][fg * 8];
        }
        #pragma unroll
        for (int m = 0; m < 4; ++m)
            #pragma unroll
            for (int n = 0; n < 2; ++n) {
                a1[m][n] = __builtin_amdgcn_mfma_f32_16x16x32_bf16(af[m], b1f[n], a1[m][n], 0, 0, 0);
                a3[m][n] = __builtin_amdgcn_mfma_f32_16x16x32_bf16(af[m], b3f[n], a3[m][n], 0, 0, 0);
            }

        if (more) {
            int nb = cur ^ 1;
            *(uint4*)&Xs[nb][xr][xs] = pxa;
            *(uint4*)&Xs[nb][xr][xs + 8] = pxb;
            st_bf4(&W1s[nb][wrow][ws0 * 4], pw1[0]);
            st_bf4(&W1s[nb][wrow][(ws0 + 4) * 4], pw1[1]);
            st_bf4(&W3s[nb][wrow][ws0 * 4], pw3[0]);
            st_bf4(&W3s[nb][wrow][(ws0 + 4) * 4], pw3[1]);
        }
    }

    size_t rowbase = (size_t)(base + tt * 128);
    #pragma unroll
    for (int m = 0; m < 4; ++m)
        #pragma unroll
        for (int n = 0; n < 2; ++n)
            #pragma unroll
            for (int rr = 0; rr < 4; ++rr) {
                int lrow = wr * 64 + m * 16 + fg * 4 + rr;
                int col  = it * 64 + wc * 32 + n * 16 + fr;
                float v = silu_f(a1[m][n][rr]) * a3[m][n][rr];
                act[(rowbase + lrow) * ID + col] = f2bf(v);
            }
}

// ---------------- Kernel 5: FFN2 (MFMA bf16, dbuf, full K, XCD-affine) ----------------
// 1D grid 1024: e = bid&7, r = bid>>3, ht = r&15, tt = r>>4.
__global__ __launch_bounds__(256) void ffn2_kernel(
    const unsigned short* __restrict__ act, const float* __restrict__ w2,
    const int* __restrict__ counts, const int* __restrict__ offs,
    const int* __restrict__ slot_token, const float* __restrict__ slot_weight,
    float* __restrict__ out)
{
    int bid = blockIdx.x;
    int e = bid & 7;
    int r = bid >> 3;
    int ht = r & 15, tt = r >> 4;
    int cnt = counts[e];
    if (tt * 128 >= cnt) return;
    int base = offs[e];

    __shared__ unsigned short As[2][128][40];
    __shared__ unsigned short Bs[2][64][40];

    int t = threadIdx.x;
    int ar = t >> 1, as = (t & 1) * 16;
    const unsigned short* aptr = act + (size_t)(base + tt * 128 + ar) * ID;
    int wrow = t >> 2, ws0 = t & 3;
    const float* w2ptr = w2 + ((size_t)e * HD + (size_t)ht * 64 + wrow) * ID;

    int wid = t >> 6, lane = t & 63;
    int wr = wid >> 1, wc = wid & 1;
    int fr = lane & 15, fg = lane >> 4;

    f32x4 acc[4][2];
    #pragma unroll
    for (int m = 0; m < 4; ++m)
        #pragma unroll
        for (int n = 0; n < 2; ++n) acc[m][n] = (f32x4){0.f, 0.f, 0.f, 0.f};

    uint4 pav[2];
    float4 pbv[2];
    pav[0] = *(const uint4*)(aptr + as);
    pav[1] = *(const uint4*)(aptr + as + 8);
    pbv[0] = *(const float4*)(w2ptr + ws0 * 4);
    pbv[1] = *(const float4*)(w2ptr + (ws0 + 4) * 4);
    *(uint4*)&As[0][ar][as] = pav[0];
    *(uint4*)&As[0][ar][as + 8] = pav[1];
    st_bf4(&Bs[0][wrow][ws0 * 4], pbv[0]);
    st_bf4(&Bs[0][wrow][(ws0 + 4) * 4], pbv[1]);

    #pragma unroll 2
    for (int kt = 0; kt < ID; kt += 32) {
        int cur = (kt >> 5) & 1;
        __syncthreads();
        bool more = (kt + 32) < ID;
        if (more) {
            int kn = kt + 32;
            pav[0] = *(const uint4*)(aptr + kn + as);
            pav[1] = *(const uint4*)(aptr + kn + as + 8);
            pbv[0] = *(const float4*)(w2ptr + kn + ws0 * 4);
            pbv[1] = *(const float4*)(w2ptr + kn + (ws0 + 4) * 4);
        }

        bf16x8 af[4], bf[2];
        #pragma unroll
        for (int m = 0; m < 4; ++m)
            af[m] = *(const bf16x8*)&As[cur][wr * 64 + m * 16 + fr][fg * 8];
        #pragma unroll
        for (int n = 0; n < 2; ++n)
            bf[n] = *(const bf16x8*)&Bs[cur][wc * 32 + n * 16 + fr][fg * 8];
        #pragma unroll
        for (int m = 0; m < 4; ++m)
            #pragma unroll
            for (int n = 0; n < 2; ++n)
                acc[m][n] = __builtin_amdgcn_mfma_f32_16x16x32_bf16(af[m], bf[n], acc[m][n], 0, 0, 0);

        if (more) {
            int nb = cur ^ 1;
            *(uint4*)&As[nb][ar][as] = pav[0];
            *(uint4*)&As[nb][ar][as + 8] = pav[1];
            st_bf4(&Bs[nb][wrow][ws0 * 4], pbv[0]);
            st_bf4(&Bs[nb][wrow][(ws0 + 4) * 4], pbv[1]);
        }
    }

    #pragma unroll
    for (int m = 0; m < 4; ++m)
        #pragma unroll
        for (int rr = 0; rr < 4; ++rr) {
            int grow = tt * 128 + wr * 64 + m * 16 + fg * 4 + rr;
            if (grow < cnt) {
                int tok  = slot_token[base + grow];
                float wv = slot_weight[base + grow];
                float* orow = out + (size_t)tok * HD + ht * 64 + wc * 32;
                #pragma unroll
                for (int n = 0; n < 2; ++n)
                    atomicAdd(&orow[n * 16 + fr], wv * acc[m][n][rr]);
            }
        }
}

// ---------------- host launch ----------------
extern "C" void kernel_launch(void* const* d_in, const int* in_sizes, int n_in,
                              void* d_out, int out_size, void* d_ws, size_t ws_size,
                              hipStream_t stream)
{
    const float* x  = (const float*)d_in[0];  // (1,1024,1024)
    const float* gw = (const float*)d_in[1];  // (8,1024)
    const float* w1 = (const float*)d_in[2];  // (8,2048,1024)
    const float* w2 = (const float*)d_in[3];  // (8,1024,2048)
    const float* w3 = (const float*)d_in[4];  // (8,2048,1024)
    float* out = (float*)d_out;

    char* w = (char*)d_ws;
    int*   counts      = (int*)(w + 0);
    int*   offs        = (int*)(w + 64);
    int*   cursor      = (int*)(w + 128);
    int*   sel         = (int*)(w + 256);
    float* wgt         = (float*)(w + 256 + 8192);
    int*   slot_token  = (int*)(w + 16640);
    float* slot_weight = (float*)(w + 16640 + 4 * MAXSLOT);
    unsigned short* xbf = (unsigned short*)(w + 65536);               // 2 MB
    unsigned short* act = (unsigned short*)(w + 65536 + 2 * TT * HD); // 12.6 MB

    hipMemsetAsync(counts, 0, 64, stream);
    hipMemsetAsync(d_out, 0, (size_t)TT * HD * sizeof(float), stream);

    cvtx_kernel<<<TT * HD / 1024, 256, 0, stream>>>(x, xbf);
    gate_kernel<<<TT / 4, 256, 0, stream>>>(x, gw, sel, wgt, counts);
    offsets_kernel<<<1, 1, 0, stream>>>(counts, offs, cursor);
    scatter_kernel<<<TT / 256, 256, 0, stream>>>(sel, wgt, cursor, slot_token, slot_weight);
    ffn1_kernel<<<2048, 256, 0, stream>>>(xbf, w1, w3, counts, offs, slot_token, act);
    ffn2_kernel<<<1024, 256, 0, stream>>>(act, w2, counts, offs, slot_token, slot_weight, out);
}

// Round 5
// 152.462 us; speedup vs baseline: 2.3330x; 1.1772x over previous
//
#include <hip/hip_runtime.h>
#include <hip/hip_bf16.h>
#include <math.h>

// Problem constants
#define TT 1024      // tokens (B*S)
#define HD 1024      // hidden
#define NE 8         // experts
#define ID 2048      // intermediate
#define MAXSLOT 3072
constexpr float JEPS = 0.01f;

typedef __attribute__((ext_vector_type(8))) short bf16x8;
typedef __attribute__((ext_vector_type(4))) float f32x4;

__device__ __forceinline__ float silu_f(float v) {
    return v / (1.f + expf(-v));
}

__device__ __forceinline__ unsigned short f2bf(float f) {
    unsigned int u = __float_as_uint(f);
    u += 0x7FFF + ((u >> 16) & 1);
    return (unsigned short)(u >> 16);
}

// packed fp32x4 -> bf16x4 store (v_cvt_pk_bf16_f32 path), p 8B aligned
__device__ __forceinline__ void st_bf4(unsigned short* p, float4 v) {
    __hip_bfloat162 lo = __float22bfloat162_rn(make_float2(v.x, v.y));
    __hip_bfloat162 hi = __float22bfloat162_rn(make_float2(v.z, v.w));
    union { __hip_bfloat162 h[2]; uint2 q; } pk;
    pk.h[0] = lo; pk.h[1] = hi;
    *(uint2*)p = pk.q;
}

// ---------------- Kernel 1: gating (one wave per token) + x->bf16 fused ----------------
__global__ __launch_bounds__(256) void gate_kernel(
    const float* __restrict__ x, const float* __restrict__ gw,
    int* __restrict__ sel, float* __restrict__ wgt, int* __restrict__ counts,
    unsigned short* __restrict__ xbf)
{
    int wave = threadIdx.x >> 6;
    int lane = threadIdx.x & 63;
    int t = blockIdx.x * 4 + wave;

    const float4* x4 = (const float4*)(x + (size_t)t * HD);
    const float4* g4 = (const float4*)gw;

    float acc[8] = {0.f,0.f,0.f,0.f,0.f,0.f,0.f,0.f};
    #pragma unroll
    for (int c = 0; c < 4; ++c) {
        float4 xv = x4[lane + c * 64];
        st_bf4(&xbf[(size_t)t * HD + (size_t)(lane + c * 64) * 4], xv);
        #pragma unroll
        for (int e = 0; e < 8; ++e) {
            float4 gv = g4[e * 256 + lane + c * 64];
            acc[e] += xv.x*gv.x + xv.y*gv.y + xv.z*gv.z + xv.w*gv.w;
        }
    }
    #pragma unroll
    for (int e = 0; e < 8; ++e) {
        float v = acc[e];
        #pragma unroll
        for (int off = 32; off > 0; off >>= 1) v += __shfl_xor(v, off, 64);
        acc[e] = v;
    }

    if (lane == 0) {
        float s[8];
        #pragma unroll
        for (int e = 0; e < 8; ++e) s[e] = acc[e];

        int i0 = 0; float t1 = s[0];
        #pragma unroll
        for (int e = 1; e < 8; ++e) { if (s[e] > t1) { t1 = s[e]; i0 = e; } }
        int i1 = -1; float t2 = -INFINITY;
        #pragma unroll
        for (int e = 0; e < 8; ++e) {
            if (e == i0) continue;
            if (s[e] > t2) { t2 = s[e]; i1 = e; }
        }

        float sum1 = 0.f;
        #pragma unroll
        for (int e = 0; e < 8; ++e) {
            if (e == i0) { sum1 += 1.f; continue; }
            float f = fmaxf(fabsf(s[e]), t1);
            bool masked = (t1 - s[e]) > 2.f * JEPS * f;
            if (!masked) sum1 += expf(s[e] - t1);
        }
        float w0 = 1.f / sum1;

        float sum2 = 0.f;
        #pragma unroll
        for (int e = 0; e < 8; ++e) {
            if (e == i0) continue;
            if (e == i1) { sum2 += 1.f; continue; }
            float f = fmaxf(fabsf(s[e]), t2);
            bool masked = (t2 - s[e]) > 2.f * JEPS * f;
            if (!masked) sum2 += expf(s[e] - t2);
        }
        float w1v = 1.f / sum2;

        sel[t * 2 + 0] = i0; sel[t * 2 + 1] = i1;
        wgt[t * 2 + 0] = w0; wgt[t * 2 + 1] = w1v;
        atomicAdd(&counts[i0], 1);
        atomicAdd(&counts[i1], 1);
    }
}

// ---------------- Kernel 2: padded prefix offsets (pad to 128) ----------------
__global__ void offsets_kernel(const int* __restrict__ counts,
                               int* __restrict__ offs, int* __restrict__ cursor)
{
    int o = 0;
    for (int e = 0; e < NE; ++e) {
        offs[e] = o;
        cursor[e] = o;
        o += (counts[e] + 127) & ~127;
    }
}

// ---------------- Kernel 3: scatter tokens to expert slots ----------------
__global__ __launch_bounds__(256) void scatter_kernel(
    const int* __restrict__ sel, const float* __restrict__ wgt,
    int* __restrict__ cursor, int* __restrict__ slot_token,
    float* __restrict__ slot_weight)
{
    int t = blockIdx.x * 256 + threadIdx.x;
    #pragma unroll
    for (int j = 0; j < 2; ++j) {
        int e = sel[t * 2 + j];
        int pos = atomicAdd(&cursor[e], 1);
        slot_token[pos] = t;
        slot_weight[pos] = wgt[t * 2 + j];
    }
}

// ---------------- Kernel 4: FFN1 (MFMA bf16, depth-2 reg prefetch, XCD-affine) ----------------
// 1D grid 2048: e = bid&7 (XCD), r = bid>>3, it = r&31, tt = r>>5.
// Tile 128 slots x 64 intermediate, BK=32 (hand-unrolled x2).
__global__ __launch_bounds__(256) void ffn1_kernel(
    const unsigned short* __restrict__ xbf, const float* __restrict__ w1,
    const float* __restrict__ w3, const int* __restrict__ counts,
    const int* __restrict__ offs, const int* __restrict__ slot_token,
    unsigned short* __restrict__ act)
{
    int bid = blockIdx.x;
    int e = bid & 7;
    int r = bid >> 3;
    int it = r & 31, tt = r >> 5;
    int cnt = counts[e];
    if (tt * 128 >= cnt) return;
    int base = offs[e];

    __shared__ unsigned short Xs[2][128][40];
    __shared__ unsigned short W1s[2][64][40];
    __shared__ unsigned short W3s[2][64][40];

    int t = threadIdx.x;
    int xr = t >> 1, xs = (t & 1) * 16;
    int srow = tt * 128 + xr;
    int tok = (srow < cnt) ? slot_token[base + srow] : slot_token[base];
    const unsigned short* xptr = xbf + (size_t)tok * HD;
    int wrow = t >> 2, ws0 = t & 3;
    const float* w1ptr = w1 + ((size_t)e * ID + (size_t)it * 64 + wrow) * HD;
    const float* w3ptr = w3 + ((size_t)e * ID + (size_t)it * 64 + wrow) * HD;

    int wid = t >> 6, lane = t & 63;
    int wr = wid >> 1, wc = wid & 1;
    int fr = lane & 15, fg = lane >> 4;

    f32x4 a1[4][2], a3[4][2];
    #pragma unroll
    for (int m = 0; m < 4; ++m)
        #pragma unroll
        for (int n = 0; n < 2; ++n) {
            a1[m][n] = (f32x4){0.f, 0.f, 0.f, 0.f};
            a3[m][n] = (f32x4){0.f, 0.f, 0.f, 0.f};
        }

    // two named register sets (depth-2 prefetch; no runtime indexing -> stays in VGPRs)
    uint4 pxa0, pxb0, pxa1, pxb1;
    float4 pw10[2], pw30[2], pw11[2], pw31[2];

#define F1_LOAD0(KT) do { \
    pxa0 = *(const uint4*)(xptr + (KT) + xs); \
    pxb0 = *(const uint4*)(xptr + (KT) + xs + 8); \
    pw10[0] = *(const float4*)(w1ptr + (KT) + ws0 * 4); \
    pw10[1] = *(const float4*)(w1ptr + (KT) + (ws0 + 4) * 4); \
    pw30[0] = *(const float4*)(w3ptr + (KT) + ws0 * 4); \
    pw30[1] = *(const float4*)(w3ptr + (KT) + (ws0 + 4) * 4); \
} while (0)
#define F1_LOAD1(KT) do { \
    pxa1 = *(const uint4*)(xptr + (KT) + xs); \
    pxb1 = *(const uint4*)(xptr + (KT) + xs + 8); \
    pw11[0] = *(const float4*)(w1ptr + (KT) + ws0 * 4); \
    pw11[1] = *(const float4*)(w1ptr + (KT) + (ws0 + 4) * 4); \
    pw31[0] = *(const float4*)(w3ptr + (KT) + ws0 * 4); \
    pw31[1] = *(const float4*)(w3ptr + (KT) + (ws0 + 4) * 4); \
} while (0)
#define F1_STORE0(B) do { \
    *(uint4*)&Xs[B][xr][xs] = pxa0; \
    *(uint4*)&Xs[B][xr][xs + 8] = pxb0; \
    st_bf4(&W1s[B][wrow][ws0 * 4], pw10[0]); \
    st_bf4(&W1s[B][wrow][(ws0 + 4) * 4], pw10[1]); \
    st_bf4(&W3s[B][wrow][ws0 * 4], pw30[0]); \
    st_bf4(&W3s[B][wrow][(ws0 + 4) * 4], pw30[1]); \
} while (0)
#define F1_STORE1(B) do { \
    *(uint4*)&Xs[B][xr][xs] = pxa1; \
    *(uint4*)&Xs[B][xr][xs + 8] = pxb1; \
    st_bf4(&W1s[B][wrow][ws0 * 4], pw11[0]); \
    st_bf4(&W1s[B][wrow][(ws0 + 4) * 4], pw11[1]); \
    st_bf4(&W3s[B][wrow][ws0 * 4], pw31[0]); \
    st_bf4(&W3s[B][wrow][(ws0 + 4) * 4], pw31[1]); \
} while (0)
#define F1_COMPUTE(B) do { \
    bf16x8 af[4], b1f[2], b3f[2]; \
    _Pragma("unroll") for (int m = 0; m < 4; ++m) \
        af[m] = *(const bf16x8*)&Xs[B][wr * 64 + m * 16 + fr][fg * 8]; \
    _Pragma("unroll") for (int n = 0; n < 2; ++n) { \
        b1f[n] = *(const bf16x8*)&W1s[B][wc * 32 + n * 16 + fr][fg * 8]; \
        b3f[n] = *(const bf16x8*)&W3s[B][wc * 32 + n * 16 + fr][fg * 8]; } \
    _Pragma("unroll") for (int m = 0; m < 4; ++m) \
        _Pragma("unroll") for (int n = 0; n < 2; ++n) { \
            a1[m][n] = __builtin_amdgcn_mfma_f32_16x16x32_bf16(af[m], b1f[n], a1[m][n], 0, 0, 0); \
            a3[m][n] = __builtin_amdgcn_mfma_f32_16x16x32_bf16(af[m], b3f[n], a3[m][n], 0, 0, 0); } \
} while (0)

    // prologue: step0 -> set0 -> LDS[0]; step1 -> set1 (in flight)
    F1_LOAD0(0);
    F1_LOAD1(32);
    F1_STORE0(0);

    for (int kt = 0; kt < HD; kt += 64) {
        // phase A: compute step kt from LDS[0]
        __syncthreads();
        if (kt + 64 < HD) F1_LOAD0(kt + 64);   // step kt+2 -> set0
        F1_COMPUTE(0);
        F1_STORE1(1);                           // step kt+1 regs -> LDS[1]
        // phase B: compute step kt+32 from LDS[1]
        __syncthreads();
        if (kt + 96 < HD) F1_LOAD1(kt + 96);   // step kt+3 -> set1
        F1_COMPUTE(1);
        if (kt + 64 < HD) F1_STORE0(0);        // step kt+2 regs -> LDS[0]
    }
#undef F1_LOAD0
#undef F1_LOAD1
#undef F1_STORE0
#undef F1_STORE1
#undef F1_COMPUTE

    size_t rowbase = (size_t)(base + tt * 128);
    #pragma unroll
    for (int m = 0; m < 4; ++m)
        #pragma unroll
        for (int n = 0; n < 2; ++n)
            #pragma unroll
            for (int rr = 0; rr < 4; ++rr) {
                int lrow = wr * 64 + m * 16 + fg * 4 + rr;
                int col  = it * 64 + wc * 32 + n * 16 + fr;
                float v = silu_f(a1[m][n][rr]) * a3[m][n][rr];
                act[(rowbase + lrow) * ID + col] = f2bf(v);
            }
}

// ---------------- Kernel 5: FFN2 (MFMA bf16, depth-2 reg prefetch, XCD-affine) ----------------
// 1D grid 1024: e = bid&7, r = bid>>3, ht = r&15, tt = r>>4. K = 2048, BK=32.
__global__ __launch_bounds__(256) void ffn2_kernel(
    const unsigned short* __restrict__ act, const float* __restrict__ w2,
    const int* __restrict__ counts, const int* __restrict__ offs,
    const int* __restrict__ slot_token, const float* __restrict__ slot_weight,
    float* __restrict__ out)
{
    int bid = blockIdx.x;
    int e = bid & 7;
    int r = bid >> 3;
    int ht = r & 15, tt = r >> 4;
    int cnt = counts[e];
    if (tt * 128 >= cnt) return;
    int base = offs[e];

    __shared__ unsigned short As[2][128][40];
    __shared__ unsigned short Bs[2][64][40];

    int t = threadIdx.x;
    int ar = t >> 1, as = (t & 1) * 16;
    const unsigned short* aptr = act + (size_t)(base + tt * 128 + ar) * ID;
    int wrow = t >> 2, ws0 = t & 3;
    const float* w2ptr = w2 + ((size_t)e * HD + (size_t)ht * 64 + wrow) * ID;

    int wid = t >> 6, lane = t & 63;
    int wr = wid >> 1, wc = wid & 1;
    int fr = lane & 15, fg = lane >> 4;

    f32x4 acc[4][2];
    #pragma unroll
    for (int m = 0; m < 4; ++m)
        #pragma unroll
        for (int n = 0; n < 2; ++n) acc[m][n] = (f32x4){0.f, 0.f, 0.f, 0.f};

    uint4 pa00, pa01, pa10, pa11;
    float4 pb0[2], pb1[2];

#define F2_LOAD0(KT) do { \
    pa00 = *(const uint4*)(aptr + (KT) + as); \
    pa01 = *(const uint4*)(aptr + (KT) + as + 8); \
    pb0[0] = *(const float4*)(w2ptr + (KT) + ws0 * 4); \
    pb0[1] = *(const float4*)(w2ptr + (KT) + (ws0 + 4) * 4); \
} while (0)
#define F2_LOAD1(KT) do { \
    pa10 = *(const uint4*)(aptr + (KT) + as); \
    pa11 = *(const uint4*)(aptr + (KT) + as + 8); \
    pb1[0] = *(const float4*)(w2ptr + (KT) + ws0 * 4); \
    pb1[1] = *(const float4*)(w2ptr + (KT) + (ws0 + 4) * 4); \
} while (0)
#define F2_STORE0(B) do { \
    *(uint4*)&As[B][ar][as] = pa00; \
    *(uint4*)&As[B][ar][as + 8] = pa01; \
    st_bf4(&Bs[B][wrow][ws0 * 4], pb0[0]); \
    st_bf4(&Bs[B][wrow][(ws0 + 4) * 4], pb0[1]); \
} while (0)
#define F2_STORE1(B) do { \
    *(uint4*)&As[B][ar][as] = pa10; \
    *(uint4*)&As[B][ar][as + 8] = pa11; \
    st_bf4(&Bs[B][wrow][ws0 * 4], pb1[0]); \
    st_bf4(&Bs[B][wrow][(ws0 + 4) * 4], pb1[1]); \
} while (0)
#define F2_COMPUTE(B) do { \
    bf16x8 af[4], bf[2]; \
    _Pragma("unroll") for (int m = 0; m < 4; ++m) \
        af[m] = *(const bf16x8*)&As[B][wr * 64 + m * 16 + fr][fg * 8]; \
    _Pragma("unroll") for (int n = 0; n < 2; ++n) \
        bf[n] = *(const bf16x8*)&Bs[B][wc * 32 + n * 16 + fr][fg * 8]; \
    _Pragma("unroll") for (int m = 0; m < 4; ++m) \
        _Pragma("unroll") for (int n = 0; n < 2; ++n) \
            acc[m][n] = __builtin_amdgcn_mfma_f32_16x16x32_bf16(af[m], bf[n], acc[m][n], 0, 0, 0); \
} while (0)

    F2_LOAD0(0);
    F2_LOAD1(32);
    F2_STORE0(0);

    for (int kt = 0; kt < ID; kt += 64) {
        __syncthreads();
        if (kt + 64 < ID) F2_LOAD0(kt + 64);
        F2_COMPUTE(0);
        F2_STORE1(1);
        __syncthreads();
        if (kt + 96 < ID) F2_LOAD1(kt + 96);
        F2_COMPUTE(1);
        if (kt + 64 < ID) F2_STORE0(0);
    }
#undef F2_LOAD0
#undef F2_LOAD1
#undef F2_STORE0
#undef F2_STORE1
#undef F2_COMPUTE

    #pragma unroll
    for (int m = 0; m < 4; ++m)
        #pragma unroll
        for (int rr = 0; rr < 4; ++rr) {
            int grow = tt * 128 + wr * 64 + m * 16 + fg * 4 + rr;
            if (grow < cnt) {
                int tok  = slot_token[base + grow];
                float wv = slot_weight[base + grow];
                float* orow = out + (size_t)tok * HD + ht * 64 + wc * 32;
                #pragma unroll
                for (int n = 0; n < 2; ++n)
                    atomicAdd(&orow[n * 16 + fr], wv * acc[m][n][rr]);
            }
        }
}

// ---------------- host launch ----------------
extern "C" void kernel_launch(void* const* d_in, const int* in_sizes, int n_in,
                              void* d_out, int out_size, void* d_ws, size_t ws_size,
                              hipStream_t stream)
{
    const float* x  = (const float*)d_in[0];  // (1,1024,1024)
    const float* gw = (const float*)d_in[1];  // (8,1024)
    const float* w1 = (const float*)d_in[2];  // (8,2048,1024)
    const float* w2 = (const float*)d_in[3];  // (8,1024,2048)
    const float* w3 = (const float*)d_in[4];  // (8,2048,1024)
    float* out = (float*)d_out;

    char* w = (char*)d_ws;
    int*   counts      = (int*)(w + 0);
    int*   offs        = (int*)(w + 64);
    int*   cursor      = (int*)(w + 128);
    int*   sel         = (int*)(w + 256);
    float* wgt         = (float*)(w + 256 + 8192);
    int*   slot_token  = (int*)(w + 16640);
    float* slot_weight = (float*)(w + 16640 + 4 * MAXSLOT);
    unsigned short* xbf = (unsigned short*)(w + 65536);               // 2 MB
    unsigned short* act = (unsigned short*)(w + 65536 + 2 * TT * HD); // 12.6 MB

    hipMemsetAsync(counts, 0, 64, stream);
    hipMemsetAsync(d_out, 0, (size_t)TT * HD * sizeof(float), stream);

    gate_kernel<<<TT / 4, 256, 0, stream>>>(x, gw, sel, wgt, counts, xbf);
    offsets_kernel<<<1, 1, 0, stream>>>(counts, offs, cursor);
    scatter_kernel<<<TT / 256, 256, 0, stream>>>(sel, wgt, cursor, slot_token, slot_weight);
    ffn1_kernel<<<2048, 256, 0, stream>>>(xbf, w1, w3, counts, offs, slot_token, act);
    ffn2_kernel<<<1024, 256, 0, stream>>>(act, w2, counts, offs, slot_token, slot_weight, out);
}